// Round 8
// baseline (46.046 us; speedup 1.0000x reference)
//
#include <hip/hip_runtime.h>

// HashEmbedding: out[t,d] = sum_h emb[x[t,h]/RATIO][d] * wt[x[t,h] + h*(K+1)]
// x [65536,3] int32; emb [10001,256] f32; wt [300003] f32; out [65536,256] f32.
//
// R8: LDS-staged gathers. i8 table (prologue quant) sliced into 16 columns of
// 16 dims; each block (1024 thr, 1/CU) stages its 160,016 B slice into LDS,
// then serves all gathers from LDS (bank-swizzled). Global traffic in main =
// 67 MB stream-write + 1.6 MB sequential reads + staging (L2/L3-amortized).
// Fallbacks: R5 i8x4 kernel if dynamic-LDS attribute fails; f32 direct if ws
// too small.

#define NUM_HASHES 3
#define EMBED_DIM 256
#define KVOCAB 100000
#define RATIO 10
#define NROWS (KVOCAB / RATIO + 1)                 // 10001
#define QTAB_BYTES ((size_t)NROWS * EMBED_DIM)     // 2,560,256
#define SCALES_OFF QTAB_BYTES
#define SCALES_BYTES ((size_t)NROWS * 4)
#define WPREP_OFF ((SCALES_OFF + SCALES_BYTES + 255) & ~(size_t)255)
#define QUANT_BLOCKS ((NROWS + 3) / 4)             // 2501
#define NSLICES 16
#define CHUNK_TOKENS 4096
#define LDS_BYTES (NROWS * 16)                     // 160,016 <= 163,840

typedef float f32x4 __attribute__((ext_vector_type(4)));

__device__ __forceinline__ float sbyte_f(unsigned int p, int j) {
    return (float)((signed char)(p >> (8 * j)));
}

// Fused prologue:
//  blocks [0, QUANT_BLOCKS): one wave per emb row -> int8 quant + scale.
//  blocks [QUANT_BLOCKS, ...): one thread per token -> wprep[t][h] = wt[...]
__global__ __launch_bounds__(256) void prologue(
    const float* __restrict__ emb,    // [NROWS, 256]
    const int*   __restrict__ x,      // [T, 3]
    const float* __restrict__ wt,     // [K*3 + 3]
    signed char* __restrict__ qt,     // [NROWS, 256]
    float*       __restrict__ scales, // [NROWS]
    float*       __restrict__ wprep,  // [T, 3]
    int nrows, int T)
{
    if ((int)blockIdx.x < QUANT_BLOCKS) {
        const int row = blockIdx.x * 4 + (threadIdx.x >> 6);
        if (row >= nrows) return;
        const int lane = threadIdx.x & 63;

        f32x4 v = __builtin_nontemporal_load(
            reinterpret_cast<const f32x4*>(emb + (size_t)row * EMBED_DIM) + lane);
        float m = fmaxf(fmaxf(fabsf(v.x), fabsf(v.y)), fmaxf(fabsf(v.z), fabsf(v.w)));
#pragma unroll
        for (int off = 32; off; off >>= 1)
            m = fmaxf(m, __shfl_xor(m, off, 64));

        const float s  = m * (1.0f / 127.0f);
        const float rs = (m > 0.f) ? (127.0f / m) : 0.f;

        const int qx = (int)rintf(v.x * rs);
        const int qy = (int)rintf(v.y * rs);
        const int qz = (int)rintf(v.z * rs);
        const int qw = (int)rintf(v.w * rs);
        const unsigned int packed = (qx & 0xff) | ((qy & 0xff) << 8) |
                                    ((qz & 0xff) << 16) | ((qw & 0xff) << 24);
        reinterpret_cast<unsigned int*>(qt + (size_t)row * EMBED_DIM)[lane] = packed;
        if (lane == 0) scales[row] = s;
    } else {
        const int t = ((int)blockIdx.x - QUANT_BLOCKS) * 256 + (int)threadIdx.x;
        if (t >= T) return;
        const int xv0 = x[(size_t)t * 3 + 0];
        const int xv1 = x[(size_t)t * 3 + 1];
        const int xv2 = x[(size_t)t * 3 + 2];
        wprep[(size_t)t * 3 + 0] = wt[xv0];
        wprep[(size_t)t * 3 + 1] = wt[xv1 + (KVOCAB + 1)];
        wprep[(size_t)t * 3 + 2] = wt[xv2 + 2 * (KVOCAB + 1)];
    }
}

// LDS-staged main. blockIdx = slice (16) x chunk (16). Block stages its
// 16-dim i8 column slice (NROWS x 16 B, dword-rotated by row for bank spread)
// into LDS, then waves process 16 tokens x 4 dword-slots each.
__global__ __launch_bounds__(1024) void hash_emb_lds(
    const int*         __restrict__ x,      // [T, 3]
    const signed char* __restrict__ qt,     // [NROWS, 256]
    const float*       __restrict__ scales, // [NROWS]
    const float*       __restrict__ wprep,  // [T, 3]
    float*             __restrict__ out,    // [T, 256]
    int T)
{
    extern __shared__ unsigned char lds_raw[];
    unsigned int* lds32 = reinterpret_cast<unsigned int*>(lds_raw);

    const int slice = blockIdx.x & (NSLICES - 1);
    const int chunk = blockIdx.x >> 4;

    // ---- stage slice into LDS (rows strided by 1024 threads) ----
    for (int r = threadIdx.x; r < NROWS; r += 1024) {
        const uint4 v = *reinterpret_cast<const uint4*>(
                            qt + (size_t)r * EMBED_DIM + slice * 16);
        const int rot = r & 3;          // store dword d at position (d+rot)&3
        uint4 w;
        if      (rot == 0) w = v;
        else if (rot == 1) w = make_uint4(v.w, v.x, v.y, v.z);
        else if (rot == 2) w = make_uint4(v.z, v.w, v.x, v.y);
        else               w = make_uint4(v.y, v.z, v.w, v.x);
        reinterpret_cast<uint4*>(lds_raw + (size_t)r * 16)[0] = w;
    }
    __syncthreads();

    const int lane = threadIdx.x & 63;
    const int wid  = threadIdx.x >> 6;      // 0..15
    const int slot = lane & 3;              // dword slot within 16-dim slice
    const int tsub = lane >> 2;             // 0..15 token within wave

#pragma unroll 2
    for (int it = 0; it < CHUNK_TOKENS / 256; ++it) {
        const int tok = chunk * CHUNK_TOKENS + it * 256 + wid * 16 + tsub;
        if (tok >= T) continue;

        const int xv0 = x[(size_t)tok * 3 + 0];
        const int xv1 = x[(size_t)tok * 3 + 1];
        const int xv2 = x[(size_t)tok * 3 + 2];
        const float w0 = wprep[(size_t)tok * 3 + 0];
        const float w1 = wprep[(size_t)tok * 3 + 1];
        const float w2 = wprep[(size_t)tok * 3 + 2];

        const int i0 = (int)((unsigned)xv0 / RATIO);
        const int i1 = (int)((unsigned)xv1 / RATIO);
        const int i2 = (int)((unsigned)xv2 / RATIO);

        const unsigned int p0 = lds32[i0 * 4 + ((slot + i0) & 3)];
        const unsigned int p1 = lds32[i1 * 4 + ((slot + i1) & 3)];
        const unsigned int p2 = lds32[i2 * 4 + ((slot + i2) & 3)];

        const float ws0 = w0 * scales[i0];
        const float ws1 = w1 * scales[i1];
        const float ws2 = w2 * scales[i2];

        f32x4 acc;
        acc.x = sbyte_f(p0, 0) * ws0 + sbyte_f(p1, 0) * ws1 + sbyte_f(p2, 0) * ws2;
        acc.y = sbyte_f(p0, 1) * ws0 + sbyte_f(p1, 1) * ws1 + sbyte_f(p2, 1) * ws2;
        acc.z = sbyte_f(p0, 2) * ws0 + sbyte_f(p1, 2) * ws1 + sbyte_f(p2, 2) * ws2;
        acc.w = sbyte_f(p0, 3) * ws0 + sbyte_f(p1, 3) * ws1 + sbyte_f(p2, 3) * ws2;

        __builtin_nontemporal_store(acc,
            reinterpret_cast<f32x4*>(out + (size_t)tok * EMBED_DIM
                                         + slice * 16 + slot * 4));
    }
}

// Fallback main (R5 structure): 4 tokens/wave, gathers from global i8 table.
__global__ __launch_bounds__(256) void hash_emb_i8x4(
    const int*         __restrict__ x,
    const signed char* __restrict__ qt,
    const float*       __restrict__ scales,
    const float*       __restrict__ wt,
    float*             __restrict__ out,
    int T)
{
    int tb = ((blockIdx.x * 256 + threadIdx.x) >> 6) * 4;
    if (tb >= T) return;
    tb = __builtin_amdgcn_readfirstlane(tb);
    const int lane = threadIdx.x & 63;

    const int* xp = x + (size_t)tb * NUM_HASHES;
    int xv[12];
#pragma unroll
    for (int i = 0; i < 12; ++i) xv[i] = xp[i];

    unsigned int p[4][3];
    int idx[4][3];
#pragma unroll
    for (int t = 0; t < 4; ++t)
#pragma unroll
        for (int h = 0; h < NUM_HASHES; ++h) {
            idx[t][h] = (int)((unsigned)xv[t * 3 + h] / RATIO);
            p[t][h] = reinterpret_cast<const unsigned int*>(
                          qt + (size_t)idx[t][h] * EMBED_DIM)[lane];
        }

    float ws[4][3];
#pragma unroll
    for (int t = 0; t < 4; ++t)
#pragma unroll
        for (int h = 0; h < NUM_HASHES; ++h)
            ws[t][h] = wt[xv[t * 3 + h] + h * (KVOCAB + 1)] * scales[idx[t][h]];

#pragma unroll
    for (int t = 0; t < 4; ++t) {
        f32x4 acc;
        acc.x = sbyte_f(p[t][0], 0) * ws[t][0] + sbyte_f(p[t][1], 0) * ws[t][1] + sbyte_f(p[t][2], 0) * ws[t][2];
        acc.y = sbyte_f(p[t][0], 1) * ws[t][0] + sbyte_f(p[t][1], 1) * ws[t][1] + sbyte_f(p[t][2], 1) * ws[t][2];
        acc.z = sbyte_f(p[t][0], 2) * ws[t][0] + sbyte_f(p[t][1], 2) * ws[t][1] + sbyte_f(p[t][2], 2) * ws[t][2];
        acc.w = sbyte_f(p[t][0], 3) * ws[t][0] + sbyte_f(p[t][1], 3) * ws[t][1] + sbyte_f(p[t][2], 3) * ws[t][2];
        __builtin_nontemporal_store(acc,
            reinterpret_cast<f32x4*>(out + (size_t)(tb + t) * EMBED_DIM) + lane);
    }
}

// Fallback (f32 table direct) if ws is too small.
__global__ __launch_bounds__(256) void hash_emb_f32(
    const int*   __restrict__ x,
    const float* __restrict__ emb,
    const float* __restrict__ wt,
    float*       __restrict__ out,
    int T)
{
    const int token = blockIdx.x * 4 + (threadIdx.x >> 6);
    if (token >= T) return;
    const int lane = threadIdx.x & 63;

    const int* xp = x + (size_t)token * NUM_HASHES;
    f32x4 acc = {0.f, 0.f, 0.f, 0.f};
#pragma unroll
    for (int h = 0; h < NUM_HASHES; ++h) {
        const int   xv = xp[h];
        const float wv = wt[xv + h * (KVOCAB + 1)];
        const f32x4 e  = reinterpret_cast<const f32x4*>(
                             emb + (size_t)((unsigned)xv / RATIO) * EMBED_DIM)[lane];
        acc.x += e.x * wv; acc.y += e.y * wv; acc.z += e.z * wv; acc.w += e.w * wv;
    }
    __builtin_nontemporal_store(acc,
        reinterpret_cast<f32x4*>(out + (size_t)token * EMBED_DIM) + lane);
}

extern "C" void kernel_launch(void* const* d_in, const int* in_sizes, int n_in,
                              void* d_out, int out_size, void* d_ws, size_t ws_size,
                              hipStream_t stream) {
    const int*   x   = (const int*)d_in[0];
    const float* emb = (const float*)d_in[1];
    const float* wt  = (const float*)d_in[2];
    float*       out = (float*)d_out;

    const int T = in_sizes[0] / NUM_HASHES;   // 65536 tokens
    const size_t wprep_bytes = (size_t)T * 3 * 4;
    const size_t ws_need = WPREP_OFF + wprep_bytes;

    if (ws_size >= ws_need) {
        signed char* qt     = (signed char*)d_ws;
        float*       scales = (float*)((char*)d_ws + SCALES_OFF);
        float*       wprep  = (float*)((char*)d_ws + WPREP_OFF);

        const int prep_blocks = (T + 255) / 256;
        hipLaunchKernelGGL(prologue, dim3(QUANT_BLOCKS + prep_blocks), dim3(256), 0, stream,
                           emb, x, wt, qt, scales, wprep, NROWS, T);

        // opt into >64KB dynamic LDS (host-side, deterministic, capture-safe)
        const hipError_t attr_err = hipFuncSetAttribute(
            (const void*)hash_emb_lds,
            hipFuncAttributeMaxDynamicSharedMemorySize, LDS_BYTES);

        if (attr_err == hipSuccess) {
            const int chunks = (T + CHUNK_TOKENS - 1) / CHUNK_TOKENS;  // 16
            hipLaunchKernelGGL(hash_emb_lds, dim3(chunks * NSLICES), dim3(1024),
                               LDS_BYTES, stream,
                               x, qt, scales, wprep, out, T);
        } else {
            const int waves  = (T + 3) / 4;
            const int blocks = (waves + 3) / 4;
            hipLaunchKernelGGL(hash_emb_i8x4, dim3(blocks), dim3(256), 0, stream,
                               x, qt, scales, wt, out, T);
        }
    } else {
        const int blocks = (T + 3) / 4;
        hipLaunchKernelGGL(hash_emb_f32, dim3(blocks), dim3(256), 0, stream,
                           x, emb, wt, out, T);
    }
}

// Round 9
// 24.734 us; speedup vs baseline: 1.8616x; 1.8616x over previous
//
#include <hip/hip_runtime.h>

// HashEmbedding: out[t,d] = sum_h emb[x[t,h]/RATIO][d] * wt[x[t,h] + h*(K+1)]
// x [65536,3] int32; emb [10001,256] f32; wt [300003] f32; out [65536,256] f32.
//
// R9: R5 structure (i8 table + 4 tokens/wave, best so far) with streaming
// stores via inline asm `sc0 sc1 nt` (system-scope write-through,
// non-temporal) so the 67 MB output burst does not allocate/evict in the
// per-XCD L2 -> the 2.6 MB i8 table stays L2-resident and gathers stop
// crossing the fabric.

#define NUM_HASHES 3
#define EMBED_DIM 256
#define KVOCAB 100000
#define RATIO 10
#define NROWS (KVOCAB / RATIO + 1)              // 10001
#define QTAB_BYTES ((size_t)NROWS * EMBED_DIM)  // 2,560,256
#define WS_NEED (QTAB_BYTES + (size_t)NROWS * 4)

typedef float f32x4 __attribute__((ext_vector_type(4)));

__device__ __forceinline__ float sbyte_f(unsigned int p, int j) {
    return (float)((signed char)(p >> (8 * j)));
}

// Streaming store: write-through system scope + non-temporal -> no L2 alloc.
__device__ __forceinline__ void store_stream(float* p, f32x4 v) {
    asm volatile("global_store_dwordx4 %0, %1, off sc0 sc1 nt"
                 :: "v"(p), "v"(v) : "memory");
}

// One wave per row: load 1 KB row, wave-reduce |max|, quantize to int8.
__global__ __launch_bounds__(256) void quant_rows_i8(
    const float* __restrict__ emb,   // [NROWS, 256]
    signed char* __restrict__ qt,    // [NROWS, 256]
    float*       __restrict__ scales,// [NROWS]
    int nrows)
{
    const int row = blockIdx.x * 4 + (threadIdx.x >> 6);
    if (row >= nrows) return;
    const int lane = threadIdx.x & 63;

    f32x4 v = __builtin_nontemporal_load(
        reinterpret_cast<const f32x4*>(emb + (size_t)row * EMBED_DIM) + lane);
    float m = fmaxf(fmaxf(fabsf(v.x), fabsf(v.y)), fmaxf(fabsf(v.z), fabsf(v.w)));
#pragma unroll
    for (int off = 32; off; off >>= 1)
        m = fmaxf(m, __shfl_xor(m, off, 64));

    const float s  = m * (1.0f / 127.0f);
    const float rs = (m > 0.f) ? (127.0f / m) : 0.f;

    const int qx = (int)rintf(v.x * rs);
    const int qy = (int)rintf(v.y * rs);
    const int qz = (int)rintf(v.z * rs);
    const int qw = (int)rintf(v.w * rs);
    const unsigned int packed = (qx & 0xff) | ((qy & 0xff) << 8) |
                                ((qz & 0xff) << 16) | ((qw & 0xff) << 24);
    reinterpret_cast<unsigned int*>(qt + (size_t)row * EMBED_DIM)[lane] = packed;
    if (lane == 0) scales[row] = s;
}

// One wave per 4 consecutive tokens, fully unrolled. Lane owns 4 contiguous
// dims of each token (dword gather = 4 int8 dims; 256B contiguous per gather).
__global__ __launch_bounds__(256) void hash_emb_i8x4(
    const int*         __restrict__ x,      // [T, 3]
    const signed char* __restrict__ qt,     // [NROWS, 256] int8
    const float*       __restrict__ scales, // [NROWS]
    const float*       __restrict__ wt,     // [K*3 + 3]
    float*             __restrict__ out,    // [T, 256]
    int T)
{
    int tb = ((blockIdx.x * 256 + threadIdx.x) >> 6) * 4;   // token base for wave
    if (tb >= T) return;
    tb = __builtin_amdgcn_readfirstlane(tb);                // SGPR -> s_load path
    const int lane = threadIdx.x & 63;

    const int* xp = x + (size_t)tb * NUM_HASHES;
    int xv[12];
#pragma unroll
    for (int i = 0; i < 12; ++i) xv[i] = xp[i];             // wave-uniform scalar loads

    // issue all 12 gathers (independent, fill the memory pipe)
    unsigned int p[4][3];
    int idx[4][3];
#pragma unroll
    for (int t = 0; t < 4; ++t)
#pragma unroll
        for (int h = 0; h < NUM_HASHES; ++h) {
            idx[t][h] = (int)((unsigned)xv[t * 3 + h] / RATIO);
            p[t][h] = reinterpret_cast<const unsigned int*>(
                          qt + (size_t)idx[t][h] * EMBED_DIM)[lane];
        }

    // per-sample weights x row scales (wave-uniform scalar loads)
    float ws[4][3];
#pragma unroll
    for (int t = 0; t < 4; ++t)
#pragma unroll
        for (int h = 0; h < NUM_HASHES; ++h)
            ws[t][h] = wt[xv[t * 3 + h] + h * (KVOCAB + 1)] * scales[idx[t][h]];

#pragma unroll
    for (int t = 0; t < 4; ++t) {
        f32x4 acc;
        acc.x = sbyte_f(p[t][0], 0) * ws[t][0] + sbyte_f(p[t][1], 0) * ws[t][1] + sbyte_f(p[t][2], 0) * ws[t][2];
        acc.y = sbyte_f(p[t][0], 1) * ws[t][0] + sbyte_f(p[t][1], 1) * ws[t][1] + sbyte_f(p[t][2], 1) * ws[t][2];
        acc.z = sbyte_f(p[t][0], 2) * ws[t][0] + sbyte_f(p[t][1], 2) * ws[t][1] + sbyte_f(p[t][2], 2) * ws[t][2];
        acc.w = sbyte_f(p[t][0], 3) * ws[t][0] + sbyte_f(p[t][1], 3) * ws[t][1] + sbyte_f(p[t][2], 3) * ws[t][2];
        store_stream(out + (size_t)(tb + t) * EMBED_DIM + lane * 4, acc);
    }
}

// Fallback (f32 table direct) if ws is too small.
__global__ __launch_bounds__(256) void hash_emb_f32(
    const int*   __restrict__ x,
    const float* __restrict__ emb,
    const float* __restrict__ wt,
    float*       __restrict__ out,
    int T)
{
    const int token = blockIdx.x * 4 + (threadIdx.x >> 6);
    if (token >= T) return;
    const int lane = threadIdx.x & 63;

    const int* xp = x + (size_t)token * NUM_HASHES;
    f32x4 acc = {0.f, 0.f, 0.f, 0.f};
#pragma unroll
    for (int h = 0; h < NUM_HASHES; ++h) {
        const int   xv = xp[h];
        const float wv = wt[xv + h * (KVOCAB + 1)];
        const f32x4 e  = reinterpret_cast<const f32x4*>(
                             emb + (size_t)((unsigned)xv / RATIO) * EMBED_DIM)[lane];
        acc.x += e.x * wv; acc.y += e.y * wv; acc.z += e.z * wv; acc.w += e.w * wv;
    }
    store_stream(out + (size_t)token * EMBED_DIM + lane * 4, acc);
}

extern "C" void kernel_launch(void* const* d_in, const int* in_sizes, int n_in,
                              void* d_out, int out_size, void* d_ws, size_t ws_size,
                              hipStream_t stream) {
    const int*   x   = (const int*)d_in[0];
    const float* emb = (const float*)d_in[1];
    const float* wt  = (const float*)d_in[2];
    float*       out = (float*)d_out;

    const int T = in_sizes[0] / NUM_HASHES;   // 65536 tokens

    if (ws_size >= WS_NEED) {
        signed char* qt     = (signed char*)d_ws;
        float*       scales = (float*)((char*)d_ws + QTAB_BYTES);
        hipLaunchKernelGGL(quant_rows_i8, dim3((NROWS + 3) / 4), dim3(256), 0, stream,
                           emb, qt, scales, NROWS);
        const int waves  = (T + 3) / 4;       // 4 tokens per wave
        const int blocks = (waves + 3) / 4;   // 4 waves per block -> 4096 blocks
        hipLaunchKernelGGL(hash_emb_i8x4, dim3(blocks), dim3(256), 0, stream,
                           x, qt, scales, wt, out, T);
    } else {
        const int blocks = (T + 3) / 4;
        hipLaunchKernelGGL(hash_emb_f32, dim3(blocks), dim3(256), 0, stream,
                           x, emb, wt, out, T);
    }
}